// Round 1
// baseline (1733.052 us; speedup 1.0000x reference)
//
#include <hip/hip_runtime.h>
#include <math.h>

#define NB 32
#define NN 1000
#define SS 200
#define DD 128
#define HH 8
#define DKK 16
#define FFD 512
#define NLAYER 3
#define LQ 802
#define MROWS (NB*LQ)      // 25664
#define RTILE 16
#define NBLK (MROWS/RTILE) // 1604 exactly

// ---------------- unselect + pos (inverse map) ----------------
__global__ __launch_bounds__(1024) void k_unselect(const int* __restrict__ sel,
                                                   int* __restrict__ unselect,
                                                   int* __restrict__ pos) {
  int b = blockIdx.x;
  int n = threadIdx.x;
  __shared__ int bufA[1024];
  __shared__ int bufB[1024];
  bufA[n] = (n < NN) ? 1 : 0;
  __syncthreads();
  if (n < SS) bufA[sel[b*SS + n]] = 0;
  __syncthreads();
  int flag = bufA[n];
  int* src = bufA; int* dst = bufB;
  for (int off = 1; off < 1024; off <<= 1) {
    int v = src[n];
    if (n >= off) v += src[n - off];
    __syncthreads();
    dst[n] = v;
    __syncthreads();
    int* tp = src; src = dst; dst = tp;
  }
  if (n < NN) {
    if (flag) {
      int j = src[n] - 1;               // exclusive scan = count of unselected before n
      unselect[b*800 + j] = n;
      pos[b*NN + n] = j + 1;            // logits position
    } else {
      pos[b*NN + n] = -1;
    }
  }
}

// ---------------- build X = [ef, left, el] ----------------
__global__ __launch_bounds__(128) void k_embed(const float* __restrict__ data,
                       const int* __restrict__ sel, const int* __restrict__ unselect,
                       const float* __restrict__ Wfirst, const float* __restrict__ bfirst,
                       const float* __restrict__ Wlast, const float* __restrict__ blast,
                       float* __restrict__ X) {
  int l = blockIdx.x, b = blockIdx.y, d = threadIdx.x;
  float* xout = X + ((size_t)(b*LQ + l))*DD;
  if (l == 0 || l == LQ-1) {
    __shared__ float xr[DD];
    int src = sel[b*SS + (l == 0 ? 0 : SS-1)];
    const float* W    = (l == 0) ? Wfirst : Wlast;
    const float* bias = (l == 0) ? bfirst : blast;
    xr[d] = data[((size_t)b*NN + src)*DD + d];
    __syncthreads();
    float acc = bias[d];
    #pragma unroll 4
    for (int k = 0; k < DD; ++k) acc += xr[k] * W[k*DD + d];
    xout[d] = acc;
  } else {
    int nidx = unselect[b*800 + (l-1)];
    xout[d] = data[((size_t)b*NN + nidx)*DD + d];
  }
}

// ---------------- fused QKV projection, head-major Q/K/V layout ----------------
__global__ __launch_bounds__(384) void k_qkv(const float* __restrict__ X,
                     const float* __restrict__ Wq, const float* __restrict__ Wk,
                     const float* __restrict__ Wv,
                     float* __restrict__ Q, float* __restrict__ K, float* __restrict__ V) {
  __shared__ float xs[RTILE][DD];
  int row0 = blockIdx.x * RTILE;
  int t = threadIdx.x;
  for (int idx = t; idx < RTILE*DD; idx += 384)
    xs[idx>>7][idx&127] = X[(size_t)(row0 + (idx>>7))*DD + (idx&127)];
  __syncthreads();
  int mi = t >> 7, cc = t & 127;
  const float* W = (mi == 0) ? Wq : (mi == 1) ? Wk : Wv;
  float acc[RTILE];
  #pragma unroll
  for (int r = 0; r < RTILE; ++r) acc[r] = 0.f;
  #pragma unroll 4
  for (int k = 0; k < DD; ++k) {
    float w = W[k*DD + cc];
    #pragma unroll
    for (int r = 0; r < RTILE; ++r) acc[r] += xs[r][k] * w;
  }
  float* Dst = (mi == 0) ? Q : (mi == 1) ? K : V;
  int h = cc >> 4, d = cc & 15;
  #pragma unroll
  for (int r = 0; r < RTILE; ++r) {
    int g = row0 + r;
    int b = g / LQ, l = g - b*LQ;
    Dst[(((size_t)(b*HH + h))*LQ + l)*DKK + d] = acc[r];
  }
}

// ---------------- attention: 1 query row / thread, online softmax ----------------
__global__ __launch_bounds__(256) void k_attn(const float* __restrict__ Q,
                      const float* __restrict__ K, const float* __restrict__ V,
                      float* __restrict__ O) {
  int b = blockIdx.z, h = blockIdx.y, qt = blockIdx.x;
  int t = threadIdx.x;
  int l = qt*256 + t;
  int lc = (l < LQ) ? l : 0;
  const size_t headoff = ((size_t)(b*HH + h))*LQ;
  __shared__ float ks[256][DKK];
  __shared__ float vs[256][DKK];
  float qv[16];
  {
    const float* qp = Q + (headoff + lc)*DKK;
    #pragma unroll
    for (int d = 0; d < 16; ++d) qv[d] = qp[d];
  }
  float o[16];
  #pragma unroll
  for (int d = 0; d < 16; ++d) o[d] = 0.f;
  float m = -INFINITY, lsum = 0.f;
  for (int j0 = 0; j0 < LQ; j0 += 256) {
    int jt = LQ - j0; if (jt > 256) jt = 256;
    for (int idx = t; idx < jt*DKK; idx += 256) {
      ks[idx>>4][idx&15] = K[(headoff + j0)*DKK + idx];
      vs[idx>>4][idx&15] = V[(headoff + j0)*DKK + idx];
    }
    __syncthreads();
    for (int jj = 0; jj < jt; ++jj) {
      const float* kp = ks[jj];
      float s = 0.f;
      #pragma unroll
      for (int d = 0; d < 16; ++d) s += qv[d]*kp[d];
      s *= 0.25f;
      const float* vp = vs[jj];
      if (s <= m) {
        float p = __expf(s - m);
        lsum += p;
        #pragma unroll
        for (int d = 0; d < 16; ++d) o[d] += p*vp[d];
      } else {
        float corr = __expf(m - s);
        m = s;
        lsum = lsum*corr + 1.f;
        #pragma unroll
        for (int d = 0; d < 16; ++d) o[d] = o[d]*corr + vp[d];
      }
    }
    __syncthreads();
  }
  if (l < LQ) {
    float inv = 1.f / lsum;
    float* op = O + ((size_t)(b*LQ + l))*DD + h*DKK;
    #pragma unroll
    for (int d = 0; d < 16; ++d) op[d] = o[d]*inv;
  }
}

// ---------------- attn output proj + residual (in-place X) ----------------
__global__ __launch_bounds__(128) void k_proj(const float* __restrict__ O,
                      const float* __restrict__ Wo, const float* __restrict__ bo,
                      float* __restrict__ X) {
  __shared__ float xs[RTILE][DD];
  int row0 = blockIdx.x * RTILE;
  int t = threadIdx.x;
  for (int idx = t; idx < RTILE*DD; idx += 128)
    xs[idx>>7][idx&127] = O[(size_t)(row0 + (idx>>7))*DD + (idx&127)];
  __syncthreads();
  float acc[RTILE];
  #pragma unroll
  for (int r = 0; r < RTILE; ++r) acc[r] = 0.f;
  #pragma unroll 4
  for (int k = 0; k < DD; ++k) {
    float w = Wo[k*DD + t];
    #pragma unroll
    for (int r = 0; r < RTILE; ++r) acc[r] += xs[r][k] * w;
  }
  float bv = bo[t];
  #pragma unroll
  for (int r = 0; r < RTILE; ++r) {
    size_t off = (size_t)(row0 + r)*DD + t;
    X[off] = X[off] + acc[r] + bv;
  }
}

// ---------------- fused FF: relu(X@W1+b1)@W2+b2 + residual (in-place X) ----------------
__global__ __launch_bounds__(512) void k_ff(const float* __restrict__ W1, const float* __restrict__ b1,
                    const float* __restrict__ W2, const float* __restrict__ b2,
                    float* __restrict__ X) {
  __shared__ float xs[RTILE][DD];   // 8 KB
  __shared__ float hs[RTILE][FFD];  // 32 KB (reused for FF2 partials)
  int row0 = blockIdx.x * RTILE;
  int t = threadIdx.x;
  for (int idx = t; idx < RTILE*DD; idx += 512)
    xs[idx>>7][idx&127] = X[(size_t)(row0 + (idx>>7))*DD + (idx&127)];
  __syncthreads();
  { // FF1: 512 cols, 1 col/thread
    float acc[RTILE];
    #pragma unroll
    for (int r = 0; r < RTILE; ++r) acc[r] = 0.f;
    #pragma unroll 4
    for (int k = 0; k < DD; ++k) {
      float w = W1[k*FFD + t];
      #pragma unroll
      for (int r = 0; r < RTILE; ++r) acc[r] += xs[r][k] * w;
    }
    float bv = b1[t];
    #pragma unroll
    for (int r = 0; r < RTILE; ++r) hs[r][t] = fmaxf(acc[r] + bv, 0.f);
  }
  __syncthreads();
  // FF2: k-split 4 ways (thread = (kg, cc))
  int cc = t & 127, kg = t >> 7;
  float acc2[RTILE];
  #pragma unroll
  for (int r = 0; r < RTILE; ++r) acc2[r] = 0.f;
  #pragma unroll 4
  for (int k2 = 0; k2 < 128; ++k2) {
    int k = kg*128 + k2;
    float w = W2[k*DD + cc];
    #pragma unroll
    for (int r = 0; r < RTILE; ++r) acc2[r] += hs[r][k] * w;
  }
  __syncthreads();                    // all hs reads done
  float* hf = &hs[0][0];
  #pragma unroll
  for (int r = 0; r < RTILE; ++r) hf[(kg*RTILE + r)*DD + cc] = acc2[r];
  __syncthreads();
  for (int idx = t; idx < RTILE*DD; idx += 512) {
    int r = idx >> 7, c = idx & 127;
    float sum = hf[(0*RTILE + r)*DD + c] + hf[(1*RTILE + r)*DD + c]
              + hf[(2*RTILE + r)*DD + c] + hf[(3*RTILE + r)*DD + c];
    size_t off = (size_t)(row0 + r)*DD + c;
    X[off] = xs[r][c] + sum + b2[c];
  }
}

// ---------------- logits = X @ Wfin + bfin ----------------
__global__ __launch_bounds__(128) void k_logits(const float* __restrict__ X,
                        const float* __restrict__ Wfin, const float* __restrict__ bfin,
                        float* __restrict__ logits) {
  int row = blockIdx.x, t = threadIdx.x;
  float v = X[(size_t)row*DD + t] * Wfin[t];
  #pragma unroll
  for (int off = 32; off > 0; off >>= 1) v += __shfl_down(v, off);
  __shared__ float s2[2];
  if ((t & 63) == 0) s2[t >> 6] = v;
  __syncthreads();
  if (t == 0) logits[row] = s2[0] + s2[1] + bfin[0];
}

// ---------------- bias add, softmax, epsilon, scatter ----------------
__global__ __launch_bounds__(256) void k_final(const float* __restrict__ logits,
                       const float* __restrict__ AB, const int* __restrict__ sel,
                       const int* __restrict__ unselect, const int* __restrict__ pos,
                       float* __restrict__ out) {
  int b = blockIdx.x, t = threadIdx.x;
  __shared__ float sl[800];
  __shared__ float red[256];
  int lastsel = sel[b*SS + SS-1];
  const float* abrow = AB + ((size_t)b*NN + lastsel)*NN;
  for (int j = t; j < 800; j += 256)
    sl[j] = logits[b*LQ + j + 1] + abrow[unselect[b*800 + j]];
  __syncthreads();
  float lm = -INFINITY;
  for (int j = t; j < 800; j += 256) lm = fmaxf(lm, sl[j]);
  red[t] = lm;
  __syncthreads();
  for (int s = 128; s > 0; s >>= 1) {
    if (t < s) red[t] = fmaxf(red[t], red[t+s]);
    __syncthreads();
  }
  float m = red[0];
  __syncthreads();
  float ls = 0.f;
  for (int j = t; j < 800; j += 256) ls += __expf(sl[j] - m);
  red[t] = ls;
  __syncthreads();
  for (int s = 128; s > 0; s >>= 1) {
    if (t < s) red[t] += red[t+s];
    __syncthreads();
  }
  float inv = 1.f / red[0];
  for (int n = t; n < NN; n += 256) {
    int p1 = pos[b*NN + n];
    float v = -2.0f;
    if (p1 >= 0) {
      float p = __expf(sl[p1-1] - m) * inv;
      if (p <= 1e-5f) p += 1e-7f;
      v = p;
    }
    out[(size_t)b*NN + n] = v;
  }
}

extern "C" void kernel_launch(void* const* d_in, const int* in_sizes, int n_in,
                              void* d_out, int out_size, void* d_ws, size_t ws_size,
                              hipStream_t stream) {
  const float* data   = (const float*)d_in[0];
  const float* AB     = (const float*)d_in[1];
  const float* Wfirst = (const float*)d_in[2];
  const float* bfirst = (const float*)d_in[3];
  const float* Wlast  = (const float*)d_in[4];
  const float* blast  = (const float*)d_in[5];
  const float* Wq     = (const float*)d_in[6];
  const float* Wk     = (const float*)d_in[7];
  const float* Wv     = (const float*)d_in[8];
  const float* Wo     = (const float*)d_in[9];
  const float* bo     = (const float*)d_in[10];
  const float* W1     = (const float*)d_in[11];
  const float* b1     = (const float*)d_in[12];
  const float* W2     = (const float*)d_in[13];
  const float* b2     = (const float*)d_in[14];
  const float* Wfin   = (const float*)d_in[15];
  const float* bfin   = (const float*)d_in[16];
  const int*   sel    = (const int*)d_in[17];
  float* out = (float*)d_out;
  (void)in_sizes; (void)n_in; (void)out_size; (void)ws_size;

  char* ws = (char*)d_ws;
  const size_t NELT = (size_t)MROWS * DD;     // 3,284,992 floats
  int*   UNSEL = (int*)ws;                    // 25600 ints
  int*   POS   = (int*)(ws + 102400);         // 32000 ints  (ends at 230400 B)
  float* X     = (float*)(ws + 230400);
  float* Qb    = X  + NELT;
  float* Kb    = Qb + NELT;
  float* Vb    = Kb + NELT;
  float* Ob    = Vb + NELT;
  float* LOG   = Ob + NELT;                   // 25664 floats; total ~63 MB

  k_unselect<<<NB, 1024, 0, stream>>>(sel, UNSEL, POS);
  k_embed<<<dim3(LQ, NB), 128, 0, stream>>>(data, sel, UNSEL, Wfirst, bfirst, Wlast, blast, X);
  for (int i = 0; i < NLAYER; ++i) {
    k_qkv <<<NBLK, 384, 0, stream>>>(X, Wq + (size_t)i*DD*DD, Wk + (size_t)i*DD*DD,
                                     Wv + (size_t)i*DD*DD, Qb, Kb, Vb);
    k_attn<<<dim3(4, HH, NB), 256, 0, stream>>>(Qb, Kb, Vb, Ob);
    k_proj<<<NBLK, 128, 0, stream>>>(Ob, Wo + (size_t)i*DD*DD, bo + (size_t)i*DD, X);
    k_ff  <<<NBLK, 512, 0, stream>>>(W1 + (size_t)i*DD*FFD, b1 + (size_t)i*FFD,
                                     W2 + (size_t)i*FFD*DD, b2 + (size_t)i*DD, X);
  }
  k_logits<<<MROWS, 128, 0, stream>>>(X, Wfin, bfin, LOG);
  k_final<<<NB, 256, 0, stream>>>(LOG, AB, sel, UNSEL, POS, out);
}